// Round 16
// baseline (79.193 us; speedup 1.0000x reference)
//
#include <hip/hip_runtime.h>
#include <hip/hip_fp16.h>
#include <math.h>

#define POOLSZ 7
#define GRIDG 8          // POOLSZ + 1
#define CCH  256         // channels (fixed by reference setup)
#define NBIN 256         // 8x8 spatial tiles x 4 levels (spatial-major)
#define OPP  (POOLSZ * POOLSZ)   // 49
#define MAXPER 8         // max RoIs per thread in fused sort (R <= 2048)

typedef float fx4 __attribute__((ext_vector_type(4)));

// ---- exact level computation (must match numpy bit-for-bit) ----
__device__ __forceinline__ int roi_level(const float* __restrict__ rois, int r) {
    const float x1 = rois[r * 5 + 1];
    const float y1 = rois[r * 5 + 2];
    const float x2 = rois[r * 5 + 3];
    const float y2 = rois[r * 5 + 4];
    const float h = __fadd_rn(__fsub_rn(y2, y1), 1.0f);
    const float w = __fadd_rn(__fsub_rn(x2, x1), 1.0f);
    const float s = __fsqrt_rn(__fmul_rn(h, w));
    const float LOG2 = __uint_as_float(0x3F317218u);   // np.float32(np.log(2.0))
    float lv = floorf(__fadd_rn(__fdiv_rn(logf(__fdiv_rn(s, 224.0f)), LOG2), 4.0f));
    lv = fminf(fmaxf(lv, 2.0f), 5.0f);
    return (int)lv;
}

// ---- sort: spatial-major (8x8 tile), level-minor; scan; scatter ----
__device__ __forceinline__ void do_sort(const float* __restrict__ rois,
                                        const float* __restrict__ im_info,
                                        int R, int* __restrict__ sorted,
                                        char* lds, int t)
{
    int* cnt = (int*)lds;
    int* tmp = cnt + NBIN;
    cnt[t] = 0;
    __syncthreads();
    int myR[MAXPER], myBin[MAXPER], mySlot[MAXPER];
    int m = 0;
    const float ih = im_info[0], iw = im_info[1];
    for (int r = t; r < R && m < MAXPER; r += 256) {
        const int lvl = roi_level(rois, r);
        const float cx = 0.5f * (rois[r * 5 + 1] + rois[r * 5 + 3]);
        const float cy = 0.5f * (rois[r * 5 + 2] + rois[r * 5 + 4]);
        const int tx = min(7, max(0, (int)(cx * 8.0f / iw)));
        const int ty = min(7, max(0, (int)(cy * 8.0f / ih)));
        // spatial-major, level-minor: temporal locality + cost mixing
        const int bin = (ty * 8 + tx) * 4 + (lvl - 2);
        myR[m] = r; myBin[m] = bin;
        mySlot[m] = atomicAdd(&cnt[bin], 1);
        ++m;
    }
    __syncthreads();
    const int v = cnt[t];
    tmp[t] = v;
    __syncthreads();
    for (int s = 1; s < NBIN; s <<= 1) {
        const int u = (t >= s) ? tmp[t - s] : 0;
        __syncthreads();
        tmp[t] += u;
        __syncthreads();
    }
    cnt[t] = tmp[t] - v;   // exclusive offsets
    __syncthreads();
    for (int i = 0; i < m; ++i)
        sorted[cnt[myBin[i]] + mySlot[i]] = myR[i];
}

// ---- transpose one 64x64 tile: [C,HW] f32 -> [HW,C] fp16 ----
__device__ __forceinline__ void do_tile(const float* __restrict__ src,
                                        __half* __restrict__ dst,
                                        int HW, int jj, int t, char* lds)
{
    float* tile = (float*)lds;   // [64][65]
    const int ptiles = HW / 64;
    const int pt = jj % ptiles, ct = jj / ptiles;
    const int pbase = pt * 64, cbase = ct * 64;
    const int l = t & 15, cr = t >> 4;
#pragma unroll
    for (int p = 0; p < 4; ++p) {
        const int c = p * 16 + cr;
        const fx4* sp = (const fx4*)(src + (size_t)(cbase + c) * HW + pbase + l * 4);
        const fx4 v = __builtin_nontemporal_load(sp);   // p* never reused
        tile[c * 65 + l * 4 + 0] = v.x;
        tile[c * 65 + l * 4 + 1] = v.y;
        tile[c * 65 + l * 4 + 2] = v.z;
        tile[c * 65 + l * 4 + 3] = v.w;
    }
    __syncthreads();
    const int ch2 = t & 31, pr = t >> 5;
#pragma unroll
    for (int p = 0; p < 8; ++p) {
        const int row = p * 8 + pr;
        const __half2 h = __floats2half2_rn(tile[(ch2 * 2) * 65 + row],
                                            tile[(ch2 * 2 + 1) * 65 + row]);
        *(__half2*)(dst + (size_t)(pbase + row) * CCH + cbase + ch2 * 2) = h;  // cached
    }
}

// ---- RoI body (r12-verified): channel-pair half2 gathers + row-group split,
//      f32 LDS stage in exact output layout, block barrier, fx4 nt drain ----
__device__ __forceinline__ void process_roi(
    int r, const __half* __restrict__ feat, int H,
    const float* __restrict__ rois, const float* __restrict__ im_info,
    float* __restrict__ out, char* lds, int t)
{
    const int W = H;
    const int cpair = t & 127;        // channel pair id: channels 2c, 2c+1
    const int grp   = t >> 7;         // row group (wave-uniform)
    const int c0    = cpair * 2;

    const float x1 = rois[r * 5 + 1];
    const float y1 = rois[r * 5 + 2];
    const float x2 = rois[r * 5 + 3];
    const float y2 = rois[r * 5 + 4];
    const float im_h  = im_info[0];
    const float scale = __fdiv_rn((float)H, im_h);
    const float ylo = __fmul_rn(y1, scale), yhi = __fmul_rn(y2, scale);
    const float xlo = __fmul_rn(x1, scale), xhi = __fmul_rn(x2, scale);

    float wx[GRIDG];
    int xoff[GRIDG], dxo[GRIDG];
#pragma unroll
    for (int i = 0; i < GRIDG; ++i) {
        const float tf = __fdiv_rn((float)i, (float)(GRIDG - 1));
        float tx = __fadd_rn(xlo, __fmul_rn(__fsub_rn(xhi, xlo), tf));
        tx = fminf(fmaxf(tx, 0.0f), (float)(W - 1));
        const float x0f = floorf(tx);
        const int   x0  = (int)x0f;
        xoff[i] = x0 * CCH;
        dxo[i]  = (min(x0 + 1, W - 1) - x0) * CCH;
        wx[i]   = __fsub_rn(tx, x0f);
    }

    float wyv[5];
    int yoff[5], dyo[5];
#pragma unroll
    for (int i = 0; i < 5; ++i) {
        const int gy = min(grp * 4 + i, GRIDG - 1);   // clamp: grp1 i=4 unused
        const float tf = __fdiv_rn((float)gy, (float)(GRIDG - 1));
        float ty = __fadd_rn(ylo, __fmul_rn(__fsub_rn(yhi, ylo), tf));
        ty = fminf(fmaxf(ty, 0.0f), (float)(H - 1));
        const float y0f = floorf(ty);
        const int   y0  = (int)y0f;
        yoff[i] = y0 * W * CCH;
        dyo[i]  = (min(y0 + 1, H - 1) - y0) * W * CCH;
        wyv[i]  = __fsub_rn(ty, y0f);
    }

    float* s_out = (float*)lds;   // exact output layout [c][49], 50176 B

    const __half* fb = feat + c0;
    float2 rowPrev[GRIDG], rowCur[GRIDG];
#pragma unroll
    for (int i = 0; i < 5; ++i) {
        if (grp == 1 && i == 4) break;   // wave-uniform
        const __half* base = fb + yoff[i];
        const int dyg = dyo[i];
        const float wyg = wyv[i];
        const float omy = 1.0f - wyg;
#pragma unroll
        for (int gx = 0; gx < GRIDG; ++gx) {
            const __half* qp = base + xoff[gx];
            const int dxg = dxo[gx];
            const float2 v00 = __half22float2(*(const __half2*)(qp));
            const float2 v01 = __half22float2(*(const __half2*)(qp + dxg));
            const float2 v10 = __half22float2(*(const __half2*)(qp + dyg));
            const float2 v11 = __half22float2(*(const __half2*)(qp + dyg + dxg));
            const float wxg = wx[gx];
            const float omx = 1.0f - wxg;
            rowCur[gx].x = omy * (omx * v00.x + wxg * v01.x)
                         + wyg * (omx * v10.x + wxg * v11.x);
            rowCur[gx].y = omy * (omx * v00.y + wxg * v01.y)
                         + wyg * (omx * v10.y + wxg * v11.y);
        }
        if (i > 0) {
            const int py = grp * 4 + i - 1;
#pragma unroll
            for (int px = 0; px < POOLSZ; ++px) {
                const float pvx = 0.25f * (rowPrev[px].x + rowPrev[px + 1].x
                                           + rowCur[px].x + rowCur[px + 1].x);
                const float pvy = 0.25f * (rowPrev[px].y + rowPrev[px + 1].y
                                           + rowCur[px].y + rowCur[px + 1].y);
                s_out[c0 * OPP + py * POOLSZ + px] = pvx;
                s_out[(c0 + 1) * OPP + py * POOLSZ + px] = pvy;
            }
        }
#pragma unroll
        for (int gx = 0; gx < GRIDG; ++gx) rowPrev[gx] = rowCur[gx];
    }

    __syncthreads();
    float* obase = out + (size_t)r * (CCH * OPP);
    const float* sp = s_out;
#pragma unroll
    for (int i = 0; i < 12; ++i) {
        const unsigned k4 = (unsigned)(i * 256 + t) * 4u;
        fx4 v;
        v.x = sp[k4 + 0]; v.y = sp[k4 + 1]; v.z = sp[k4 + 2]; v.w = sp[k4 + 3];
        __builtin_nontemporal_store(v, (fx4*)(obase + k4));
    }
    if (t < 64) {
        const unsigned k4 = (unsigned)(12 * 256 + t) * 4u;
        fx4 v;
        v.x = sp[k4 + 0]; v.y = sp[k4 + 1]; v.z = sp[k4 + 2]; v.w = sp[k4 + 3];
        __builtin_nontemporal_store(v, (fx4*)(obase + k4));
    }
}

// ---- prep: transpose all levels + sort (last block) ----
__global__ __launch_bounds__(256) void prep_kernel(
    const float* __restrict__ p2, const float* __restrict__ p3,
    const float* __restrict__ p4, const float* __restrict__ p5,
    __half* __restrict__ t2, __half* __restrict__ t3,
    __half* __restrict__ t4, __half* __restrict__ t5,
    int HW2, int HW3, int HW4, int HW5,
    const float* __restrict__ rois, const float* __restrict__ im_info,
    int R, int* __restrict__ sorted, int nblkT)
{
    __shared__ __align__(16) char lds[64 * 65 * 4];
    const int t = threadIdx.x;
    if ((int)blockIdx.x == nblkT) {
        do_sort(rois, im_info, R, sorted, lds, t);
        return;
    }
    const int n2 = (HW2 / 64) * 4, n3 = (HW3 / 64) * 4, n4 = (HW4 / 64) * 4;
    int bid = blockIdx.x;
    const float* src; __half* dst; int HW;
    if (bid < n2)              { src = p2; dst = t2; HW = HW2; }
    else if ((bid -= n2) < n3) { src = p3; dst = t3; HW = HW3; }
    else if ((bid -= n3) < n4) { src = p4; dst = t4; HW = HW4; }
    else { bid -= n4;            src = p5; dst = t5; HW = HW5; }
    do_tile(src, dst, HW, bid, t, lds);
}

// ---- persistent main: grid = ~resident capacity; blocks pop RoIs from a
//      relaxed atomic queue (1 atomicAdd per RoI, no spinning, no fences,
//      no co-residency assumption — excess blocks just schedule later). ----
__global__ __launch_bounds__(256) void fpn_main_persist(
    const __half* __restrict__ t2, const __half* __restrict__ t3,
    const __half* __restrict__ t4, const __half* __restrict__ t5,
    const float* __restrict__ rois, const float* __restrict__ im_info,
    float* __restrict__ out, const int* __restrict__ sorted,
    int* __restrict__ ctr,
    int H2, int H3, int H4, int H5, int R)
{
    __shared__ __align__(16) char lds[CCH * OPP * 4];   // 50176 B
    __shared__ int sh;
    const int t = threadIdx.x;
    for (;;) {
        if (t == 0) sh = atomicAdd(ctr, 1);
        __syncthreads();
        const int n = sh;
        if (n >= R) return;
        const int r = sorted ? sorted[n] : n;
        const int lvl = roi_level(rois, r);
        const __half* feat; int H;
        switch (lvl) {
            case 2:  feat = t2; H = H2; break;
            case 3:  feat = t3; H = H3; break;
            case 4:  feat = t4; H = H4; break;
            default: feat = t5; H = H5; break;
        }
        process_roi(r, feat, H, rois, im_info, out, lds, t);
        __syncthreads();   // drain done before next iteration's stage writes
    }
}

// ---- fallback (round-3 kernel): only if d_ws can't hold the fp16 copies ----
__global__ __launch_bounds__(256) void fpn_roialign_kernel(
    const float* __restrict__ p2, const float* __restrict__ p3,
    const float* __restrict__ p4, const float* __restrict__ p5,
    const float* __restrict__ rois, const float* __restrict__ im_info,
    float* __restrict__ out,
    int H2, int H3, int H4, int H5, int R)
{
    const int r = blockIdx.x;
    const float bf = rois[r * 5 + 0];
    const float x1 = rois[r * 5 + 1];
    const float y1 = rois[r * 5 + 2];
    const float x2 = rois[r * 5 + 3];
    const float y2 = rois[r * 5 + 4];
    const int lvl = roi_level(rois, r);
    const float* feat; int H;
    switch (lvl) {
        case 2:  feat = p2; H = H2; break;
        case 3:  feat = p3; H = H3; break;
        case 4:  feat = p4; H = H4; break;
        default: feat = p5; H = H5; break;
    }
    const int W = H;
    const int wv  = threadIdx.x >> 6;
    const int lid = threadIdx.x & 63;
    const int gy  = lid >> 3;
    const int gx  = lid & 7;
    const float im_h  = im_info[0];
    const float scale = __fdiv_rn((float)H, im_h);
    const float ylo = __fmul_rn(y1, scale), yhi = __fmul_rn(y2, scale);
    const float xlo = __fmul_rn(x1, scale), xhi = __fmul_rn(x2, scale);
    float ty = __fadd_rn(ylo, __fmul_rn(__fsub_rn(yhi, ylo),
                                        __fdiv_rn((float)gy, (float)(GRIDG - 1))));
    ty = fminf(fmaxf(ty, 0.0f), (float)(H - 1));
    float tx = __fadd_rn(xlo, __fmul_rn(__fsub_rn(xhi, xlo),
                                        __fdiv_rn((float)gx, (float)(GRIDG - 1))));
    tx = fminf(fmaxf(tx, 0.0f), (float)(W - 1));
    const float y0f = floorf(ty), x0f = floorf(tx);
    const int   y0  = (int)y0f,   x0  = (int)x0f;
    const int   y1i = min(y0 + 1, H - 1);
    const int   x1i = min(x0 + 1, W - 1);
    const float wyv = __fsub_rn(ty, y0f);
    const float wxv = __fsub_rn(tx, x0f);
    const float omy = 1.0f - wyv;
    const float omx = 1.0f - wxv;
    const int b = (int)bf;
    const size_t plane = (size_t)H * W;
    const float* fbase = feat + (size_t)(b * CCH + wv * 64) * plane;
    const int o00 = y0  * W + x0;
    const int o01 = y0  * W + x1i;
    const int o10 = y1i * W + x0;
    const int o11 = y1i * W + x1i;
    float* obase = out + (size_t)r * (CCH * OPP) + (size_t)(wv * 64) * OPP;
    const bool wr  = (gy < POOLSZ) && (gx < POOLSZ);
    const int oidx = gy * POOLSZ + gx;
#pragma unroll 4
    for (int k = 0; k < 64; ++k) {
        const float* f = fbase + (size_t)k * plane;
        const float v00 = f[o00];
        const float v01 = f[o01];
        const float v10 = f[o10];
        const float v11 = f[o11];
        const float v = omy * (omx * v00 + wxv * v01) + wyv * (omx * v10 + wxv * v11);
        const float vb  = __shfl_down(v, 8);
        const float vr  = __shfl_down(v, 1);
        const float vbr = __shfl_down(v, 9);
        if (wr) obase[k * OPP + oidx] = 0.25f * (((v + vb) + vr) + vbr);
    }
}

extern "C" void kernel_launch(void* const* d_in, const int* in_sizes, int n_in,
                              void* d_out, int out_size, void* d_ws, size_t ws_size,
                              hipStream_t stream) {
    const float* p2      = (const float*)d_in[0];
    const float* p3      = (const float*)d_in[1];
    const float* p4      = (const float*)d_in[2];
    const float* p5      = (const float*)d_in[3];
    const float* rois    = (const float*)d_in[4];
    const float* im_info = (const float*)d_in[5];
    float* out = (float*)d_out;

    const int R = in_sizes[4] / 5;
    auto dimOf = [](int sz) {
        int hw = sz / CCH;
        return (int)(sqrtf((float)hw) + 0.5f);
    };
    const int H2 = dimOf(in_sizes[0]);
    const int H3 = dimOf(in_sizes[1]);
    const int H4 = dimOf(in_sizes[2]);
    const int H5 = dimOf(in_sizes[3]);
    const size_t HW2 = (size_t)H2 * H2, HW3 = (size_t)H3 * H3;
    const size_t HW4 = (size_t)H4 * H4, HW5 = (size_t)H5 * H5;

    // ws: ctr (256B) | sorted[R] (pad 256) | t2 | t3 | t4 | t5 (fp16)
    const size_t ctrPad    = 256;
    const size_t sortPad   = ((size_t)R * sizeof(int) + 255) & ~(size_t)255;
    const size_t transBytes = (HW2 + HW3 + HW4 + HW5) * CCH * sizeof(__half);
    const bool canSort = (R <= 256 * MAXPER);
    const bool canRun  = ws_size >= ctrPad + sortPad + transBytes;

    if (!canRun) {
        fpn_roialign_kernel<<<R, 256, 0, stream>>>(
            p2, p3, p4, p5, rois, im_info, out, H2, H3, H4, H5, R);
        return;
    }

    int* ctr    = (int*)d_ws;
    int* sorted = canSort ? (int*)((char*)d_ws + ctrPad) : nullptr;
    __half* t2 = (__half*)((char*)d_ws + ctrPad + sortPad);
    __half* t3 = t2 + HW2 * CCH;
    __half* t4 = t3 + HW3 * CCH;
    __half* t5 = t4 + HW4 * CCH;

    hipMemsetAsync(ctr, 0, sizeof(int), stream);
    const int nblkT = (int)((HW2 + HW3 + HW4 + HW5) / 64 * 4);
    prep_kernel<<<nblkT + (canSort ? 1 : 0), 256, 0, stream>>>(
        p2, p3, p4, p5, t2, t3, t4, t5,
        (int)HW2, (int)HW3, (int)HW4, (int)HW5,
        rois, im_info, R, sorted, nblkT);

    // 3 blocks/CU resident (50 KB LDS) x 256 CUs; queue smooths the tail
    const int NPERSIST = 768;
    fpn_main_persist<<<NPERSIST, 256, 0, stream>>>(
        t2, t3, t4, t5, rois, im_info, out, sorted, ctr, H2, H3, H4, H5, R);
}

// Round 17
// 76.729 us; speedup vs baseline: 1.0321x; 1.0321x over previous
//
#include <hip/hip_runtime.h>
#include <hip/hip_fp16.h>
#include <math.h>

#define POOLSZ 7
#define GRIDG 8          // POOLSZ + 1
#define CCH  256         // channels (fixed by reference setup)
#define NBIN 256         // 8x8 spatial tiles x 4 levels (spatial-major)
#define OPP  (POOLSZ * POOLSZ)   // 49
#define MAXPER 8         // max RoIs per thread in fused sort (R <= 2048)

typedef float fx4 __attribute__((ext_vector_type(4)));

// ---- exact level computation (must match numpy bit-for-bit) ----
__device__ __forceinline__ int roi_level(const float* __restrict__ rois, int r) {
    const float x1 = rois[r * 5 + 1];
    const float y1 = rois[r * 5 + 2];
    const float x2 = rois[r * 5 + 3];
    const float y2 = rois[r * 5 + 4];
    const float h = __fadd_rn(__fsub_rn(y2, y1), 1.0f);
    const float w = __fadd_rn(__fsub_rn(x2, x1), 1.0f);
    const float s = __fsqrt_rn(__fmul_rn(h, w));
    const float LOG2 = __uint_as_float(0x3F317218u);   // np.float32(np.log(2.0))
    float lv = floorf(__fadd_rn(__fdiv_rn(logf(__fdiv_rn(s, 224.0f)), LOG2), 4.0f));
    lv = fminf(fmaxf(lv, 2.0f), 5.0f);
    return (int)lv;
}

// ---- fused transpose (all levels) + sort (last block); r14-verified ----
__global__ __launch_bounds__(256) void prep_kernel(
    const float* __restrict__ p2, const float* __restrict__ p3,
    const float* __restrict__ p4, const float* __restrict__ p5,
    __half* __restrict__ t2, __half* __restrict__ t3,
    __half* __restrict__ t4, __half* __restrict__ t5,
    int HW2, int HW3, int HW4, int HW5,
    const float* __restrict__ rois, const float* __restrict__ im_info,
    int R, int* __restrict__ sorted, int nblkT)
{
    const int t = threadIdx.x;

    if ((int)blockIdx.x == nblkT) {
        // ---------------- sort block ----------------
        __shared__ int cnt[NBIN];
        __shared__ int tmp[NBIN];
        cnt[t] = 0;
        __syncthreads();

        int myR[MAXPER], myBin[MAXPER], mySlot[MAXPER];
        int m = 0;
        const float ih = im_info[0], iw = im_info[1];
        for (int r = t; r < R && m < MAXPER; r += 256) {
            const int lvl = roi_level(rois, r);
            const float cx = 0.5f * (rois[r * 5 + 1] + rois[r * 5 + 3]);
            const float cy = 0.5f * (rois[r * 5 + 2] + rois[r * 5 + 4]);
            const int tx = min(7, max(0, (int)(cx * 8.0f / iw)));
            const int ty = min(7, max(0, (int)(cy * 8.0f / ih)));
            // spatial-major, level-minor: balances levels across XCD chunks
            const int bin = (ty * 8 + tx) * 4 + (lvl - 2);
            myR[m] = r; myBin[m] = bin;
            mySlot[m] = atomicAdd(&cnt[bin], 1);
            ++m;
        }
        __syncthreads();

        const int v = cnt[t];
        tmp[t] = v;
        __syncthreads();
        for (int s = 1; s < NBIN; s <<= 1) {
            const int u = (t >= s) ? tmp[t - s] : 0;
            __syncthreads();
            tmp[t] += u;
            __syncthreads();
        }
        cnt[t] = tmp[t] - v;   // exclusive offsets
        __syncthreads();

        for (int i = 0; i < m; ++i)
            sorted[cnt[myBin[i]] + mySlot[i]] = myR[i];
        return;
    }

    // ---------------- transpose blocks (XCD-banded mapping, r14) ----------
    const int n2 = (HW2 / 64) * 4, n3 = (HW3 / 64) * 4, n4 = (HW4 / 64) * 4;
    int bid = blockIdx.x;
    const float* src; __half* dst; int HW;
    if (bid < n2)              { src = p2; dst = t2; HW = HW2; }
    else if ((bid -= n2) < n3) { src = p3; dst = t3; HW = HW3; }
    else if ((bid -= n3) < n4) { src = p4; dst = t4; HW = HW4; }
    else { bid -= n4;            src = p5; dst = t5; HW = HW5; }
    const int ptiles = HW / 64;
    int pt, ct;
    if ((ptiles & 7) == 0) {
        const int ppb    = ptiles >> 3;       // pt's per band
        const int band   = bid & 7;
        const int within = bid >> 3;
        pt = band * ppb + (within % ppb);
        ct = within / ppb;
    } else {
        pt = bid % ptiles;
        ct = bid / ptiles;
    }
    const int pbase = pt * 64, cbase = ct * 64;

    __shared__ float tile[64][65];

    const int l = t & 15, cr = t >> 4;
#pragma unroll
    for (int p = 0; p < 4; ++p) {
        const int c = p * 16 + cr;
        const fx4* sp = (const fx4*)(src + (size_t)(cbase + c) * HW + pbase + l * 4);
        const fx4 v = __builtin_nontemporal_load(sp);
        tile[c][l * 4 + 0] = v.x;
        tile[c][l * 4 + 1] = v.y;
        tile[c][l * 4 + 2] = v.z;
        tile[c][l * 4 + 3] = v.w;
    }
    __syncthreads();

    const int ch2 = t & 31, pr = t >> 5;
#pragma unroll
    for (int p = 0; p < 8; ++p) {
        const int row = p * 8 + pr;
        const __half2 h = __floats2half2_rn(tile[ch2 * 2][row], tile[ch2 * 2 + 1][row]);
        *(__half2*)(dst + (size_t)(pbase + row) * CCH + cbase + ch2 * 2) = h;
    }
}

// ---- main kernel: 512 threads/block = (128 channel-pairs) x (4 row-groups).
//      Groups own grid rows {0-2},{2-4},{4-6},{6-7} -> pooled rows
//      {0,1},{2,3},{4,5},{6}. 8 waves/block, 50 KB LDS -> 24 waves/CU
//      (2x the 256-thread version's latency hiding; +22% gather volume). ----
__global__ __launch_bounds__(512) void fpn_main_t(
    const __half* __restrict__ t2, const __half* __restrict__ t3,
    const __half* __restrict__ t4, const __half* __restrict__ t5,
    const float* __restrict__ rois, const float* __restrict__ im_info,
    float* __restrict__ out, const int* __restrict__ order,
    int H2, int H3, int H4, int H5, int R)
{
    // bijective XCD chunk swizzle
    const int n = blockIdx.x;
    const int q = R / 8, rem = R % 8;
    const int xcd = n % 8, idx = n / 8;
    const int nsw = (xcd < rem ? xcd * (q + 1) : rem * (q + 1) + (xcd - rem) * q) + idx;
    const int r = order ? order[nsw] : nsw;
    const int t = threadIdx.x;
    const int cpair = t & 127;        // channel pair id: channels 2c, 2c+1
    const int grp   = t >> 7;         // row group 0..3 (wave-uniform)
    const int c0    = cpair * 2;

    const float x1 = rois[r * 5 + 1];
    const float y1 = rois[r * 5 + 2];
    const float x2 = rois[r * 5 + 3];
    const float y2 = rois[r * 5 + 4];

    const int lvl = roi_level(rois, r);
    const __half* feat;
    int H;
    switch (lvl) {
        case 2:  feat = t2; H = H2; break;
        case 3:  feat = t3; H = H3; break;
        case 4:  feat = t4; H = H4; break;
        default: feat = t5; H = H5; break;
    }
    const int W = H;

    // grid coords (exact numpy arithmetic on the index path)
    const float im_h  = im_info[0];
    const float scale = __fdiv_rn((float)H, im_h);
    const float ylo = __fmul_rn(y1, scale), yhi = __fmul_rn(y2, scale);
    const float xlo = __fmul_rn(x1, scale), xhi = __fmul_rn(x2, scale);

    float wx[GRIDG];
    int xoff[GRIDG], dxo[GRIDG];
#pragma unroll
    for (int i = 0; i < GRIDG; ++i) {
        const float tf = __fdiv_rn((float)i, (float)(GRIDG - 1));
        float tx = __fadd_rn(xlo, __fmul_rn(__fsub_rn(xhi, xlo), tf));
        tx = fminf(fmaxf(tx, 0.0f), (float)(W - 1));
        const float x0f = floorf(tx);
        const int   x0  = (int)x0f;
        xoff[i] = x0 * CCH;
        dxo[i]  = (min(x0 + 1, W - 1) - x0) * CCH;
        wx[i]   = __fsub_rn(tx, x0f);
    }

    // this group's grid rows: gy = grp*2 + i, i = 0..2 (group 3: i = 0..1)
    float wyv[3];
    int yoff[3], dyo[3];
#pragma unroll
    for (int i = 0; i < 3; ++i) {
        const int gy = min(grp * 2 + i, GRIDG - 1);   // clamp: grp3 i=2 unused
        const float tf = __fdiv_rn((float)gy, (float)(GRIDG - 1));
        float ty = __fadd_rn(ylo, __fmul_rn(__fsub_rn(yhi, ylo), tf));
        ty = fminf(fmaxf(ty, 0.0f), (float)(H - 1));
        const float y0f = floorf(ty);
        const int   y0  = (int)y0f;
        yoff[i] = y0 * W * CCH;
        dyo[i]  = (min(y0 + 1, H - 1) - y0) * W * CCH;
        wyv[i]  = __fsub_rn(ty, y0f);
    }

    __shared__ float s_out[CCH * OPP];   // exact output layout, 50176 B

    const __half* fb = feat + c0;
    float2 rowPrev[GRIDG], rowCur[GRIDG];
#pragma unroll
    for (int i = 0; i < 3; ++i) {
        if (grp == 3 && i == 2) break;   // wave-uniform
        const __half* base = fb + yoff[i];
        const int dyg = dyo[i];
        const float wyg = wyv[i];
        const float omy = 1.0f - wyg;
#pragma unroll
        for (int gx = 0; gx < GRIDG; ++gx) {
            const __half* qp = base + xoff[gx];
            const int dxg = dxo[gx];
            const float2 v00 = __half22float2(*(const __half2*)(qp));
            const float2 v01 = __half22float2(*(const __half2*)(qp + dxg));
            const float2 v10 = __half22float2(*(const __half2*)(qp + dyg));
            const float2 v11 = __half22float2(*(const __half2*)(qp + dyg + dxg));
            const float wxg = wx[gx];
            const float omx = 1.0f - wxg;
            rowCur[gx].x = omy * (omx * v00.x + wxg * v01.x)
                         + wyg * (omx * v10.x + wxg * v11.x);
            rowCur[gx].y = omy * (omx * v00.y + wxg * v01.y)
                         + wyg * (omx * v10.y + wxg * v11.y);
        }
        if (i > 0) {
            const int py = grp * 2 + i - 1;   // g0:{0,1} g1:{2,3} g2:{4,5} g3:{6}
#pragma unroll
            for (int px = 0; px < POOLSZ; ++px) {
                const float pvx = 0.25f * (rowPrev[px].x + rowPrev[px + 1].x
                                           + rowCur[px].x + rowCur[px + 1].x);
                const float pvy = 0.25f * (rowPrev[px].y + rowPrev[px + 1].y
                                           + rowCur[px].y + rowCur[px + 1].y);
                s_out[c0 * OPP + py * POOLSZ + px] = pvx;
                s_out[(c0 + 1) * OPP + py * POOLSZ + px] = pvy;
            }
        }
#pragma unroll
        for (int gx = 0; gx < GRIDG; ++gx) rowPrev[gx] = rowCur[gx];
    }

    __syncthreads();
    // contiguous drain: 3136 vec4s = 6 full 512-thread passes + 64-thread tail
    float* obase = out + (size_t)r * (CCH * OPP);
    const float* sp = s_out;
#pragma unroll
    for (int i = 0; i < 6; ++i) {
        const unsigned k4 = (unsigned)(i * 512 + t) * 4u;
        fx4 v;
        v.x = sp[k4 + 0]; v.y = sp[k4 + 1]; v.z = sp[k4 + 2]; v.w = sp[k4 + 3];
        __builtin_nontemporal_store(v, (fx4*)(obase + k4));
    }
    if (t < 64) {
        const unsigned k4 = (unsigned)(6 * 512 + t) * 4u;
        fx4 v;
        v.x = sp[k4 + 0]; v.y = sp[k4 + 1]; v.z = sp[k4 + 2]; v.w = sp[k4 + 3];
        __builtin_nontemporal_store(v, (fx4*)(obase + k4));
    }
}

// ---- fallback (round-3 kernel): only if d_ws can't hold the fp16 copies ----
__global__ __launch_bounds__(256) void fpn_roialign_kernel(
    const float* __restrict__ p2, const float* __restrict__ p3,
    const float* __restrict__ p4, const float* __restrict__ p5,
    const float* __restrict__ rois, const float* __restrict__ im_info,
    float* __restrict__ out,
    int H2, int H3, int H4, int H5, int R)
{
    const int r = blockIdx.x;

    const float bf = rois[r * 5 + 0];
    const float x1 = rois[r * 5 + 1];
    const float y1 = rois[r * 5 + 2];
    const float x2 = rois[r * 5 + 3];
    const float y2 = rois[r * 5 + 4];

    const int lvl = roi_level(rois, r);
    const float* feat;
    int H;
    switch (lvl) {
        case 2:  feat = p2; H = H2; break;
        case 3:  feat = p3; H = H3; break;
        case 4:  feat = p4; H = H4; break;
        default: feat = p5; H = H5; break;
    }
    const int W = H;
    const int wv  = threadIdx.x >> 6;
    const int lid = threadIdx.x & 63;
    const int gy  = lid >> 3;
    const int gx  = lid & 7;

    const float im_h  = im_info[0];
    const float scale = __fdiv_rn((float)H, im_h);
    const float ylo = __fmul_rn(y1, scale), yhi = __fmul_rn(y2, scale);
    const float xlo = __fmul_rn(x1, scale), xhi = __fmul_rn(x2, scale);
    float ty = __fadd_rn(ylo, __fmul_rn(__fsub_rn(yhi, ylo),
                                        __fdiv_rn((float)gy, (float)(GRIDG - 1))));
    ty = fminf(fmaxf(ty, 0.0f), (float)(H - 1));
    float tx = __fadd_rn(xlo, __fmul_rn(__fsub_rn(xhi, xlo),
                                        __fdiv_rn((float)gx, (float)(GRIDG - 1))));
    tx = fminf(fmaxf(tx, 0.0f), (float)(W - 1));
    const float y0f = floorf(ty), x0f = floorf(tx);
    const int   y0  = (int)y0f,   x0  = (int)x0f;
    const int   y1i = min(y0 + 1, H - 1);
    const int   x1i = min(x0 + 1, W - 1);
    const float wyv = __fsub_rn(ty, y0f);
    const float wxv = __fsub_rn(tx, x0f);
    const float omy = 1.0f - wyv;
    const float omx = 1.0f - wxv;

    const int b = (int)bf;
    const size_t plane = (size_t)H * W;
    const float* fbase = feat + (size_t)(b * CCH + wv * 64) * plane;
    const int o00 = y0  * W + x0;
    const int o01 = y0  * W + x1i;
    const int o10 = y1i * W + x0;
    const int o11 = y1i * W + x1i;

    float* obase = out + (size_t)r * (CCH * OPP) + (size_t)(wv * 64) * OPP;
    const bool wr  = (gy < POOLSZ) && (gx < POOLSZ);
    const int oidx = gy * POOLSZ + gx;

#pragma unroll 4
    for (int k = 0; k < 64; ++k) {
        const float* f = fbase + (size_t)k * plane;
        const float v00 = f[o00];
        const float v01 = f[o01];
        const float v10 = f[o10];
        const float v11 = f[o11];
        const float v = omy * (omx * v00 + wxv * v01) + wyv * (omx * v10 + wxv * v11);
        const float vb  = __shfl_down(v, 8);
        const float vr  = __shfl_down(v, 1);
        const float vbr = __shfl_down(v, 9);
        if (wr) obase[k * OPP + oidx] = 0.25f * (((v + vb) + vr) + vbr);
    }
}

extern "C" void kernel_launch(void* const* d_in, const int* in_sizes, int n_in,
                              void* d_out, int out_size, void* d_ws, size_t ws_size,
                              hipStream_t stream) {
    const float* p2      = (const float*)d_in[0];
    const float* p3      = (const float*)d_in[1];
    const float* p4      = (const float*)d_in[2];
    const float* p5      = (const float*)d_in[3];
    const float* rois    = (const float*)d_in[4];
    const float* im_info = (const float*)d_in[5];
    float* out = (float*)d_out;

    const int R = in_sizes[4] / 5;
    auto dimOf = [](int sz) {
        int hw = sz / CCH;
        return (int)(sqrtf((float)hw) + 0.5f);
    };
    const int H2 = dimOf(in_sizes[0]);
    const int H3 = dimOf(in_sizes[1]);
    const int H4 = dimOf(in_sizes[2]);
    const int H5 = dimOf(in_sizes[3]);
    const size_t HW2 = (size_t)H2 * H2, HW3 = (size_t)H3 * H3;
    const size_t HW4 = (size_t)H4 * H4, HW5 = (size_t)H5 * H5;

    // ws layout: sorted[R] ints | t2 | t3 | t4 | t5 (fp16, 256-byte aligned)
    const size_t sortBytes = (size_t)R * sizeof(int);
    const size_t sortPad   = (sortBytes + 255) & ~(size_t)255;
    const size_t transBytes = (HW2 + HW3 + HW4 + HW5) * CCH * sizeof(__half);
    const bool canSort  = (ws_size >= sortBytes) && (R <= 256 * MAXPER);
    const bool canTrans = ws_size >= sortPad + transBytes;

    if (canTrans) {
        int* sorted = canSort ? (int*)d_ws : nullptr;
        __half* t2 = (__half*)((char*)d_ws + sortPad);
        __half* t3 = t2 + HW2 * CCH;
        __half* t4 = t3 + HW3 * CCH;
        __half* t5 = t4 + HW4 * CCH;
        const int nblkT = (int)((HW2 + HW3 + HW4 + HW5) / 64 * 4);
        const int nblk  = nblkT + (canSort ? 1 : 0);
        prep_kernel<<<nblk, 256, 0, stream>>>(
            p2, p3, p4, p5, t2, t3, t4, t5,
            (int)HW2, (int)HW3, (int)HW4, (int)HW5,
            rois, im_info, R, sorted, nblkT);
        fpn_main_t<<<R, 512, 0, stream>>>(
            t2, t3, t4, t5, rois, im_info, out, sorted, H2, H3, H4, H5, R);
    } else {
        fpn_roialign_kernel<<<R, 256, 0, stream>>>(
            p2, p3, p4, p5, rois, im_info, out, H2, H3, H4, H5, R);
    }
}

// Round 18
// 61.396 us; speedup vs baseline: 1.2899x; 1.2497x over previous
//
#include <hip/hip_runtime.h>
#include <hip/hip_fp16.h>
#include <math.h>

#define POOLSZ 7
#define GRIDG 8          // POOLSZ + 1
#define CCH  256         // channels (fixed by reference setup)
#define NBIN 256         // 8x8 spatial tiles x 4 levels (spatial-major)
#define OPP  (POOLSZ * POOLSZ)   // 49
#define MAXPER 8         // max RoIs per thread in fused sort (R <= 2048)

typedef float fx4 __attribute__((ext_vector_type(4)));

// ---- exact level computation (must match numpy bit-for-bit) ----
__device__ __forceinline__ int roi_level(const float* __restrict__ rois, int r) {
    const float x1 = rois[r * 5 + 1];
    const float y1 = rois[r * 5 + 2];
    const float x2 = rois[r * 5 + 3];
    const float y2 = rois[r * 5 + 4];
    const float h = __fadd_rn(__fsub_rn(y2, y1), 1.0f);
    const float w = __fadd_rn(__fsub_rn(x2, x1), 1.0f);
    const float s = __fsqrt_rn(__fmul_rn(h, w));
    const float LOG2 = __uint_as_float(0x3F317218u);   // np.float32(np.log(2.0))
    float lv = floorf(__fadd_rn(__fdiv_rn(logf(__fdiv_rn(s, 224.0f)), LOG2), 4.0f));
    lv = fminf(fmaxf(lv, 2.0f), 5.0f);
    return (int)lv;
}

// ---- fused transpose (all levels) + sort (last block) ----
// Transpose blocks are XCD-BANDED: blockIdx%8 == image band (pt/(ptiles/8))
// of the tile, matched to main's chunked XCD swizzle (measured neutral but
// harmless; kept from r14-verified config).
__global__ __launch_bounds__(256) void prep_kernel(
    const float* __restrict__ p2, const float* __restrict__ p3,
    const float* __restrict__ p4, const float* __restrict__ p5,
    __half* __restrict__ t2, __half* __restrict__ t3,
    __half* __restrict__ t4, __half* __restrict__ t5,
    int HW2, int HW3, int HW4, int HW5,
    const float* __restrict__ rois, const float* __restrict__ im_info,
    int R, int* __restrict__ sorted, int nblkT)
{
    const int t = threadIdx.x;

    if ((int)blockIdx.x == nblkT) {
        // ---------------- sort block ----------------
        __shared__ int cnt[NBIN];
        __shared__ int tmp[NBIN];
        cnt[t] = 0;
        __syncthreads();

        int myR[MAXPER], myBin[MAXPER], mySlot[MAXPER];
        int m = 0;
        const float ih = im_info[0], iw = im_info[1];
        for (int r = t; r < R && m < MAXPER; r += 256) {
            const int lvl = roi_level(rois, r);
            const float cx = 0.5f * (rois[r * 5 + 1] + rois[r * 5 + 3]);
            const float cy = 0.5f * (rois[r * 5 + 2] + rois[r * 5 + 4]);
            const int tx = min(7, max(0, (int)(cx * 8.0f / iw)));
            const int ty = min(7, max(0, (int)(cy * 8.0f / ih)));
            // spatial-major, level-minor: balances levels across XCD chunks
            const int bin = (ty * 8 + tx) * 4 + (lvl - 2);
            myR[m] = r; myBin[m] = bin;
            mySlot[m] = atomicAdd(&cnt[bin], 1);
            ++m;
        }
        __syncthreads();

        const int v = cnt[t];
        tmp[t] = v;
        __syncthreads();
        for (int s = 1; s < NBIN; s <<= 1) {
            const int u = (t >= s) ? tmp[t - s] : 0;
            __syncthreads();
            tmp[t] += u;
            __syncthreads();
        }
        cnt[t] = tmp[t] - v;   // exclusive offsets
        __syncthreads();

        for (int i = 0; i < m; ++i)
            sorted[cnt[myBin[i]] + mySlot[i]] = myR[i];
        return;
    }

    // ---------------- transpose blocks (XCD-banded mapping) ----------------
    const int n2 = (HW2 / 64) * 4, n3 = (HW3 / 64) * 4, n4 = (HW4 / 64) * 4;
    int bid = blockIdx.x;
    const float* src; __half* dst; int HW;
    if (bid < n2)              { src = p2; dst = t2; HW = HW2; }
    else if ((bid -= n2) < n3) { src = p3; dst = t3; HW = HW3; }
    else if ((bid -= n3) < n4) { src = p4; dst = t4; HW = HW4; }
    else { bid -= n4;            src = p5; dst = t5; HW = HW5; }
    const int ptiles = HW / 64;
    int pt, ct;
    if ((ptiles & 7) == 0) {
        const int ppb    = ptiles >> 3;       // pt's per band
        const int band   = bid & 7;
        const int within = bid >> 3;          // [0, ptiles*4/8)
        pt = band * ppb + (within % ppb);
        ct = within / ppb;                    // [0,4)
    } else {
        pt = bid % ptiles;
        ct = bid / ptiles;
    }
    const int pbase = pt * 64, cbase = ct * 64;

    __shared__ float tile[64][65];

    // read: 4 passes of 16 channels, nontemporal 16B per lane (coalesced;
    // nt keeps p* out of L2 so the fp16 t* stays resident for the main kernel)
    const int l = t & 15, cr = t >> 4;
#pragma unroll
    for (int p = 0; p < 4; ++p) {
        const int c = p * 16 + cr;
        const fx4* sp = (const fx4*)(src + (size_t)(cbase + c) * HW + pbase + l * 4);
        const fx4 v = __builtin_nontemporal_load(sp);
        tile[c][l * 4 + 0] = v.x;
        tile[c][l * 4 + 1] = v.y;
        tile[c][l * 4 + 2] = v.z;
        tile[c][l * 4 + 3] = v.w;
    }
    __syncthreads();

    // write: 8 passes of 8 pixel-rows, half2 per lane (coalesced, cached)
    const int ch2 = t & 31, pr = t >> 5;
#pragma unroll
    for (int p = 0; p < 8; ++p) {
        const int row = p * 8 + pr;
        const __half2 h = __floats2half2_rn(tile[ch2 * 2][row], tile[ch2 * 2 + 1][row]);
        *(__half2*)(dst + (size_t)(pbase + row) * CCH + cbase + ch2 * 2) = h;
    }
}

// ---- main kernel: block per RoI. Thread = channel-PAIR (half2 gathers,
//      256B wave-loads) x row-group (threads 0-127: pooled rows 0-3,
//      threads 128-255: rows 4-6; wave-uniform split). f32 LDS stage in
//      exact output layout, block barrier, fx4 nt drain. r14-verified. ----
__global__ __launch_bounds__(256) void fpn_main_t(
    const __half* __restrict__ t2, const __half* __restrict__ t3,
    const __half* __restrict__ t4, const __half* __restrict__ t5,
    const float* __restrict__ rois, const float* __restrict__ im_info,
    float* __restrict__ out, const int* __restrict__ order,
    int H2, int H3, int H4, int H5, int R)
{
    // bijective XCD chunk swizzle: XCD x gets a contiguous sorted chunk
    const int n = blockIdx.x;
    const int q = R / 8, rem = R % 8;
    const int xcd = n % 8, idx = n / 8;
    const int nsw = (xcd < rem ? xcd * (q + 1) : rem * (q + 1) + (xcd - rem) * q) + idx;
    const int r = order ? order[nsw] : nsw;
    const int t = threadIdx.x;
    const int cpair = t & 127;        // channel pair id: channels 2c, 2c+1
    const int grp   = t >> 7;         // row group (wave-uniform)
    const int c0    = cpair * 2;

    const float x1 = rois[r * 5 + 1];
    const float y1 = rois[r * 5 + 2];
    const float x2 = rois[r * 5 + 3];
    const float y2 = rois[r * 5 + 4];

    const int lvl = roi_level(rois, r);
    const __half* feat;
    int H;
    switch (lvl) {
        case 2:  feat = t2; H = H2; break;
        case 3:  feat = t3; H = H3; break;
        case 4:  feat = t4; H = H4; break;
        default: feat = t5; H = H5; break;
    }
    const int W = H;

    // grid coords (exact numpy arithmetic on the index path)
    const float im_h  = im_info[0];
    const float scale = __fdiv_rn((float)H, im_h);
    const float ylo = __fmul_rn(y1, scale), yhi = __fmul_rn(y2, scale);
    const float xlo = __fmul_rn(x1, scale), xhi = __fmul_rn(x2, scale);

    float wx[GRIDG];
    int xoff[GRIDG], dxo[GRIDG];
#pragma unroll
    for (int i = 0; i < GRIDG; ++i) {
        const float tf = __fdiv_rn((float)i, (float)(GRIDG - 1));
        float tx = __fadd_rn(xlo, __fmul_rn(__fsub_rn(xhi, xlo), tf));
        tx = fminf(fmaxf(tx, 0.0f), (float)(W - 1));
        const float x0f = floorf(tx);
        const int   x0  = (int)x0f;
        xoff[i] = x0 * CCH;
        dxo[i]  = (min(x0 + 1, W - 1) - x0) * CCH;
        wx[i]   = __fsub_rn(tx, x0f);
    }

    // this group's 5 grid rows: gy = grp*4 + i (i=0..4; group 1 uses 0..3)
    float wyv[5];
    int yoff[5], dyo[5];
#pragma unroll
    for (int i = 0; i < 5; ++i) {
        const int gy = min(grp * 4 + i, GRIDG - 1);   // clamp: grp1 i=4 unused
        const float tf = __fdiv_rn((float)gy, (float)(GRIDG - 1));
        float ty = __fadd_rn(ylo, __fmul_rn(__fsub_rn(yhi, ylo), tf));
        ty = fminf(fmaxf(ty, 0.0f), (float)(H - 1));
        const float y0f = floorf(ty);
        const int   y0  = (int)y0f;
        yoff[i] = y0 * W * CCH;
        dyo[i]  = (min(y0 + 1, H - 1) - y0) * W * CCH;
        wyv[i]  = __fsub_rn(ty, y0f);
    }

    __shared__ float s_out[CCH * OPP];   // exact output layout, 50176 B

    const __half* fb = feat + c0;
    float2 rowPrev[GRIDG], rowCur[GRIDG];
#pragma unroll
    for (int i = 0; i < 5; ++i) {
        if (grp == 1 && i == 4) break;   // wave-uniform
        const __half* base = fb + yoff[i];
        const int dyg = dyo[i];
        const float wyg = wyv[i];
        const float omy = 1.0f - wyg;
#pragma unroll
        for (int gx = 0; gx < GRIDG; ++gx) {
            const __half* qp = base + xoff[gx];
            const int dxg = dxo[gx];
            const float2 v00 = __half22float2(*(const __half2*)(qp));
            const float2 v01 = __half22float2(*(const __half2*)(qp + dxg));
            const float2 v10 = __half22float2(*(const __half2*)(qp + dyg));
            const float2 v11 = __half22float2(*(const __half2*)(qp + dyg + dxg));
            const float wxg = wx[gx];
            const float omx = 1.0f - wxg;
            rowCur[gx].x = omy * (omx * v00.x + wxg * v01.x)
                         + wyg * (omx * v10.x + wxg * v11.x);
            rowCur[gx].y = omy * (omx * v00.y + wxg * v01.y)
                         + wyg * (omx * v10.y + wxg * v11.y);
        }
        if (i > 0) {
            const int py = grp * 4 + i - 1;
#pragma unroll
            for (int px = 0; px < POOLSZ; ++px) {
                const float pvx = 0.25f * (rowPrev[px].x + rowPrev[px + 1].x
                                           + rowCur[px].x + rowCur[px + 1].x);
                const float pvy = 0.25f * (rowPrev[px].y + rowPrev[px + 1].y
                                           + rowCur[px].y + rowCur[px + 1].y);
                s_out[c0 * OPP + py * POOLSZ + px] = pvx;
                s_out[(c0 + 1) * OPP + py * POOLSZ + px] = pvy;
            }
        }
#pragma unroll
        for (int gx = 0; gx < GRIDG; ++gx) rowPrev[gx] = rowCur[gx];
    }

    __syncthreads();
    // pure contiguous drain: 3136 vec4s = 12 full passes + 64-thread tail
    float* obase = out + (size_t)r * (CCH * OPP);
    const float* sp = s_out;
#pragma unroll
    for (int i = 0; i < 12; ++i) {
        const unsigned k4 = (unsigned)(i * 256 + t) * 4u;
        fx4 v;
        v.x = sp[k4 + 0]; v.y = sp[k4 + 1]; v.z = sp[k4 + 2]; v.w = sp[k4 + 3];
        __builtin_nontemporal_store(v, (fx4*)(obase + k4));
    }
    if (t < 64) {
        const unsigned k4 = (unsigned)(12 * 256 + t) * 4u;
        fx4 v;
        v.x = sp[k4 + 0]; v.y = sp[k4 + 1]; v.z = sp[k4 + 2]; v.w = sp[k4 + 3];
        __builtin_nontemporal_store(v, (fx4*)(obase + k4));
    }
}

// ---- fallback (round-3 kernel): only if d_ws can't hold the fp16 copies ----
__global__ __launch_bounds__(256) void fpn_roialign_kernel(
    const float* __restrict__ p2, const float* __restrict__ p3,
    const float* __restrict__ p4, const float* __restrict__ p5,
    const float* __restrict__ rois, const float* __restrict__ im_info,
    float* __restrict__ out,
    int H2, int H3, int H4, int H5, int R)
{
    const int r = blockIdx.x;

    const float bf = rois[r * 5 + 0];
    const float x1 = rois[r * 5 + 1];
    const float y1 = rois[r * 5 + 2];
    const float x2 = rois[r * 5 + 3];
    const float y2 = rois[r * 5 + 4];

    const int lvl = roi_level(rois, r);
    const float* feat;
    int H;
    switch (lvl) {
        case 2:  feat = p2; H = H2; break;
        case 3:  feat = p3; H = H3; break;
        case 4:  feat = p4; H = H4; break;
        default: feat = p5; H = H5; break;
    }
    const int W = H;
    const int wv  = threadIdx.x >> 6;
    const int lid = threadIdx.x & 63;
    const int gy  = lid >> 3;
    const int gx  = lid & 7;

    const float im_h  = im_info[0];
    const float scale = __fdiv_rn((float)H, im_h);
    const float ylo = __fmul_rn(y1, scale), yhi = __fmul_rn(y2, scale);
    const float xlo = __fmul_rn(x1, scale), xhi = __fmul_rn(x2, scale);
    float ty = __fadd_rn(ylo, __fmul_rn(__fsub_rn(yhi, ylo),
                                        __fdiv_rn((float)gy, (float)(GRIDG - 1))));
    ty = fminf(fmaxf(ty, 0.0f), (float)(H - 1));
    float tx = __fadd_rn(xlo, __fmul_rn(__fsub_rn(xhi, xlo),
                                        __fdiv_rn((float)gx, (float)(GRIDG - 1))));
    tx = fminf(fmaxf(tx, 0.0f), (float)(W - 1));
    const float y0f = floorf(ty), x0f = floorf(tx);
    const int   y0  = (int)y0f,   x0  = (int)x0f;
    const int   y1i = min(y0 + 1, H - 1);
    const int   x1i = min(x0 + 1, W - 1);
    const float wyv = __fsub_rn(ty, y0f);
    const float wxv = __fsub_rn(tx, x0f);
    const float omy = 1.0f - wyv;
    const float omx = 1.0f - wxv;

    const int b = (int)bf;
    const size_t plane = (size_t)H * W;
    const float* fbase = feat + (size_t)(b * CCH + wv * 64) * plane;
    const int o00 = y0  * W + x0;
    const int o01 = y0  * W + x1i;
    const int o10 = y1i * W + x0;
    const int o11 = y1i * W + x1i;

    float* obase = out + (size_t)r * (CCH * OPP) + (size_t)(wv * 64) * OPP;
    const bool wr  = (gy < POOLSZ) && (gx < POOLSZ);
    const int oidx = gy * POOLSZ + gx;

#pragma unroll 4
    for (int k = 0; k < 64; ++k) {
        const float* f = fbase + (size_t)k * plane;
        const float v00 = f[o00];
        const float v01 = f[o01];
        const float v10 = f[o10];
        const float v11 = f[o11];
        const float v = omy * (omx * v00 + wxv * v01) + wyv * (omx * v10 + wxv * v11);
        const float vb  = __shfl_down(v, 8);
        const float vr  = __shfl_down(v, 1);
        const float vbr = __shfl_down(v, 9);
        if (wr) obase[k * OPP + oidx] = 0.25f * (((v + vb) + vr) + vbr);
    }
}

extern "C" void kernel_launch(void* const* d_in, const int* in_sizes, int n_in,
                              void* d_out, int out_size, void* d_ws, size_t ws_size,
                              hipStream_t stream) {
    const float* p2      = (const float*)d_in[0];
    const float* p3      = (const float*)d_in[1];
    const float* p4      = (const float*)d_in[2];
    const float* p5      = (const float*)d_in[3];
    const float* rois    = (const float*)d_in[4];
    const float* im_info = (const float*)d_in[5];
    float* out = (float*)d_out;

    const int R = in_sizes[4] / 5;
    auto dimOf = [](int sz) {
        int hw = sz / CCH;
        return (int)(sqrtf((float)hw) + 0.5f);
    };
    const int H2 = dimOf(in_sizes[0]);
    const int H3 = dimOf(in_sizes[1]);
    const int H4 = dimOf(in_sizes[2]);
    const int H5 = dimOf(in_sizes[3]);
    const size_t HW2 = (size_t)H2 * H2, HW3 = (size_t)H3 * H3;
    const size_t HW4 = (size_t)H4 * H4, HW5 = (size_t)H5 * H5;

    // ws layout: sorted[R] ints | t2 | t3 | t4 | t5 (fp16, 256-byte aligned)
    const size_t sortBytes = (size_t)R * sizeof(int);
    const size_t sortPad   = (sortBytes + 255) & ~(size_t)255;
    const size_t transBytes = (HW2 + HW3 + HW4 + HW5) * CCH * sizeof(__half);
    const bool canSort  = (ws_size >= sortBytes) && (R <= 256 * MAXPER);
    const bool canTrans = ws_size >= sortPad + transBytes;

    if (canTrans) {
        int* sorted = canSort ? (int*)d_ws : nullptr;
        __half* t2 = (__half*)((char*)d_ws + sortPad);
        __half* t3 = t2 + HW2 * CCH;
        __half* t4 = t3 + HW3 * CCH;
        __half* t5 = t4 + HW4 * CCH;
        const int nblkT = (int)((HW2 + HW3 + HW4 + HW5) / 64 * 4);
        const int nblk  = nblkT + (canSort ? 1 : 0);
        prep_kernel<<<nblk, 256, 0, stream>>>(
            p2, p3, p4, p5, t2, t3, t4, t5,
            (int)HW2, (int)HW3, (int)HW4, (int)HW5,
            rois, im_info, R, sorted, nblkT);
        fpn_main_t<<<R, 256, 0, stream>>>(
            t2, t3, t4, t5, rois, im_info, out, sorted, H2, H3, H4, H5, R);
    } else {
        fpn_roialign_kernel<<<R, 256, 0, stream>>>(
            p2, p3, p4, p5, rois, im_info, out, H2, H3, H4, H5, R);
    }
}